// Round 1
// baseline (351.641 us; speedup 1.0000x reference)
//
#include <hip/hip_runtime.h>
#include <math.h>

// Problem constants
// NDF=512, NCF=256, NCC=256, EMB=16, FIELD=8, B=2048
// NH0=1024, CHANNEL=1017, HID=1020, K3=2041
// res layout: [2048][2048] fp32: cols 0..1023 = x, cols 1024..2040 = x_fm2, 2041..2047 = 0
// h layout:   [2048][1024] fp32: cols 0..1019 = h, 1020..1023 = 0 (never read)

// ---------------------------------------------------------------------------
// Generic tiled fp32 GEMM body: C[m0.., cbase..] = act(A(MxK) @ W(KxN) + bias)
// BM=128, BN=64, BK=16, 256 threads, 8x4 micro-tile per thread.
// ---------------------------------------------------------------------------
template<int ACT>  // 0 = relu, 1 = leaky_relu(0.01)
__device__ __forceinline__ void gemm_body(
    const float* __restrict__ A, int lda,
    const float* __restrict__ W, int ldw,
    const float* __restrict__ bias,   // indexed in W's n-space
    float* __restrict__ C, int ldc,
    int cbase,                        // column base in C for this block
    int m0, int n0, int K)
{
    __shared__ float As[16][132];  // [k][m], stride 132 -> <=2-way bank conflicts
    __shared__ float Bs[16][68];   // [k][n], stride 68 (16B-aligned rows)

    const int t  = threadIdx.x;
    const int tx = t & 15;         // 0..15 -> 4 output cols
    const int ty = t >> 4;         // 0..15 -> 8 output rows (4 + 4 offset 64)
    const int ar = t >> 2;         // A load row 0..63
    const int ak = (t & 3) << 2;   // A load col 0,4,8,12
    const int bk = t >> 4;         // W load row 0..15
    const int bc = (t & 15) << 2;  // W load col 0..60

    float acc[8][4];
    #pragma unroll
    for (int i = 0; i < 8; ++i)
        #pragma unroll
        for (int j = 0; j < 4; ++j) acc[i][j] = 0.f;

    for (int k0 = 0; k0 < K; k0 += 16) {
        const float4 a0 = *reinterpret_cast<const float4*>(A + (size_t)(m0 + ar)      * lda + k0 + ak);
        const float4 a1 = *reinterpret_cast<const float4*>(A + (size_t)(m0 + ar + 64) * lda + k0 + ak);
        const float4 b0 = *reinterpret_cast<const float4*>(W + (size_t)(k0 + bk) * ldw + n0 + bc);
        __syncthreads();  // previous tile's compute must finish before overwrite
        As[ak+0][ar]    = a0.x; As[ak+1][ar]    = a0.y; As[ak+2][ar]    = a0.z; As[ak+3][ar]    = a0.w;
        As[ak+0][ar+64] = a1.x; As[ak+1][ar+64] = a1.y; As[ak+2][ar+64] = a1.z; As[ak+3][ar+64] = a1.w;
        *reinterpret_cast<float4*>(&Bs[bk][bc]) = b0;
        __syncthreads();
        #pragma unroll
        for (int k = 0; k < 16; ++k) {
            float af[8], bf[4];
            *reinterpret_cast<float4*>(&af[0]) = *reinterpret_cast<const float4*>(&As[k][ty*4]);
            *reinterpret_cast<float4*>(&af[4]) = *reinterpret_cast<const float4*>(&As[k][ty*4 + 64]);
            *reinterpret_cast<float4*>(&bf[0]) = *reinterpret_cast<const float4*>(&Bs[k][tx*4]);
            #pragma unroll
            for (int i = 0; i < 8; ++i)
                #pragma unroll
                for (int j = 0; j < 4; ++j)
                    acc[i][j] = fmaf(af[i], bf[j], acc[i][j]);
        }
    }

    #pragma unroll
    for (int i = 0; i < 8; ++i) {
        const int r  = m0 + (ty << 2) + (i & 3) + ((i >> 2) << 6);
        const int cl = tx << 2;
        float vj[4];
        #pragma unroll
        for (int j = 0; j < 4; ++j) {
            float z = acc[i][j] + bias[n0 + cl + j];
            if (ACT == 0) z = fmaxf(z, 0.f);
            else          z = (z > 0.f) ? z : 0.01f * z;
            vj[j] = z;
        }
        float4 o; o.x = vj[0]; o.y = vj[1]; o.z = vj[2]; o.w = vj[3];
        *reinterpret_cast<float4*>(C + (size_t)r * ldc + cbase + cl) = o;
    }
}

// Top: fused x_d / x_c GEMMs -> res[:, 0:1024)
__global__ __launch_bounds__(256) void gemm_top_kernel(
    const float* __restrict__ dx, const float* __restrict__ Wd, const float* __restrict__ bd,
    const float* __restrict__ cx, const float* __restrict__ Wc, const float* __restrict__ bc_,
    float* __restrict__ res)
{
    const int m0  = blockIdx.y * 128;
    const int n0g = blockIdx.x * 64;
    if (n0g < 512)
        gemm_body<0>(dx, 512, Wd, 512, bd,  res, 2048, n0g, m0, n0g,       512);
    else
        gemm_body<0>(cx, 256, Wc, 512, bc_, res, 2048, n0g, m0, n0g - 512, 256);
}

// GEMM3: h = leaky_relu(res(2048x2041, ld 2048) @ W1p(2048x1024) + b1p)
__global__ __launch_bounds__(256) void gemm_w1_kernel(
    const float* __restrict__ res, const float* __restrict__ W1p,
    const float* __restrict__ b1p, float* __restrict__ h)
{
    gemm_body<1>(res, 2048, W1p, 1024, b1p, h, 1024, blockIdx.x * 64,
                 blockIdx.y * 128, blockIdx.x * 64, 2048);
}

// Pad W1 (2041x1020) -> W1p (2048x1024), b1 -> b1p(1024)
__global__ __launch_bounds__(256) void pad_w1_kernel(
    const float* __restrict__ W1, const float* __restrict__ b1,
    float* __restrict__ W1p, float* __restrict__ b1p)
{
    const int idx = blockIdx.x * 256 + threadIdx.x;   // over 2048*1024
    const int k = idx >> 10;
    const int n = idx & 1023;
    W1p[idx] = (k < 2041 && n < 1020) ? W1[(size_t)k * 1020 + n] : 0.f;
    if (idx < 1024) b1p[idx] = (idx < 1020) ? b1[idx] : 0.f;
}

// FM + linear term: res[:, 1024+ch] = lin + 0.5*fm   (ch >= 1017 -> 0 padding)
__global__ __launch_bounds__(256) void fm_kernel(
    const float* __restrict__ v, const float* __restrict__ lin_w,
    const float* __restrict__ lin_b, float* __restrict__ res)
{
    __shared__ float xs[1024];
    const int b = blockIdx.x;
    const int t = threadIdx.x;
    reinterpret_cast<float4*>(xs)[t] =
        reinterpret_cast<const float4*>(res + (size_t)b * 2048)[t];
    __syncthreads();

    float lw[8];
    #pragma unroll
    for (int f = 0; f < 8; ++f) lw[f] = lin_w[f];
    const float lb = lin_b[0];

    #pragma unroll
    for (int it = 0; it < 4; ++it) {
        const int ch = t + it * 256;
        float o = 0.f;
        if (ch < 1017) {
            float xw[8];
            #pragma unroll
            for (int f = 0; f < 8; ++f) xw[f] = xs[ch + f];
            float s[16], ss[16];
            #pragma unroll
            for (int e = 0; e < 16; ++e) { s[e] = 0.f; ss[e] = 0.f; }
            const float4* vp = reinterpret_cast<const float4*>(v + (size_t)ch * 128);
            #pragma unroll
            for (int f = 0; f < 8; ++f) {
                const float xf = xw[f];
                #pragma unroll
                for (int q = 0; q < 4; ++q) {
                    const float4 vv = vp[f * 4 + q];
                    float tv;
                    tv = xf * vv.x; s[q*4+0] += tv; ss[q*4+0] += tv * tv;
                    tv = xf * vv.y; s[q*4+1] += tv; ss[q*4+1] += tv * tv;
                    tv = xf * vv.z; s[q*4+2] += tv; ss[q*4+2] += tv * tv;
                    tv = xf * vv.w; s[q*4+3] += tv; ss[q*4+3] += tv * tv;
                }
            }
            float fm = 0.f;
            #pragma unroll
            for (int e = 0; e < 16; ++e) fm += s[e] * s[e] - ss[e];
            float lin = lb;
            #pragma unroll
            for (int f = 0; f < 8; ++f) lin = fmaf(xw[f], lw[f], lin);
            o = lin + 0.5f * fm;
        }
        res[(size_t)b * 2048 + 1024 + ch] = o;  // ch in [1017,1024) writes the zero pad
    }
}

// Final: out[b] = sigmoid(dot(h[b, 0:1020], W2) + b2)
__global__ __launch_bounds__(256) void final_kernel(
    const float* __restrict__ h, const float* __restrict__ W2,
    const float* __restrict__ b2, float* __restrict__ out)
{
    const int b = blockIdx.x;
    const int t = threadIdx.x;
    float sum = 0.f;
    for (int j = t; j < 1020; j += 256)
        sum = fmaf(h[(size_t)b * 1024 + j], W2[j], sum);
    #pragma unroll
    for (int off = 32; off > 0; off >>= 1)
        sum += __shfl_down(sum, off, 64);
    __shared__ float ps[4];
    if ((t & 63) == 0) ps[t >> 6] = sum;
    __syncthreads();
    if (t == 0) {
        const float z = ps[0] + ps[1] + ps[2] + ps[3] + b2[0];
        out[b] = 1.f / (1.f + expf(-z));
    }
}

extern "C" void kernel_launch(void* const* d_in, const int* in_sizes, int n_in,
                              void* d_out, int out_size, void* d_ws, size_t ws_size,
                              hipStream_t stream)
{
    const float* dx = (const float*)d_in[0];
    const float* cx = (const float*)d_in[1];
    const float* Wd = (const float*)d_in[2];
    const float* bd = (const float*)d_in[3];
    const float* Wc = (const float*)d_in[4];
    const float* bc = (const float*)d_in[5];
    const float* v  = (const float*)d_in[6];
    const float* lw = (const float*)d_in[7];
    const float* lb = (const float*)d_in[8];
    const float* W1 = (const float*)d_in[9];
    const float* b1 = (const float*)d_in[10];
    const float* W2 = (const float*)d_in[11];
    const float* b2 = (const float*)d_in[12];
    float* out = (float*)d_out;

    float* res = (float*)d_ws;                     // 2048*2048 fp32 (16 MB)
    float* h   = res + (size_t)2048 * 2048;        // 2048*1024 fp32 (8 MB)
    float* W1p = h   + (size_t)2048 * 1024;        // 2048*1024 fp32 (8 MB)
    float* b1p = W1p + (size_t)2048 * 1024;        // 1024 fp32

    hipLaunchKernelGGL(pad_w1_kernel,  dim3(8192),    dim3(256), 0, stream, W1, b1, W1p, b1p);
    hipLaunchKernelGGL(gemm_top_kernel, dim3(16, 16), dim3(256), 0, stream, dx, Wd, bd, cx, Wc, bc, res);
    hipLaunchKernelGGL(fm_kernel,      dim3(2048),    dim3(256), 0, stream, v, lw, lb, res);
    hipLaunchKernelGGL(gemm_w1_kernel, dim3(16, 16),  dim3(256), 0, stream, res, W1p, b1p, h);
    hipLaunchKernelGGL(final_kernel,   dim3(2048),    dim3(256), 0, stream, h, W2, b2, out);
}

// Round 2
// 93.099 us; speedup vs baseline: 3.7771x; 3.7771x over previous
//
#include <hip/hip_runtime.h>
#include <math.h>

// NDF=512 NCF=256 NCC=256 EMB=16 FIELD=8 B=2048
// NH0=1024 CHANNEL=1017 HID=1020 K3=2041
// resb: [2048][2048] bf16 (cols 0..1023 = x, 1024..2040 = x_fm2, 2041..2047 = 0)
// h:    [2048][1024] fp32 (cols 1020..1023 zero, never read)

typedef __bf16 bf16x8 __attribute__((ext_vector_type(8)));
typedef float  f32x4  __attribute__((ext_vector_type(4)));

__device__ __forceinline__ unsigned short f2bf(float x) {
    union { float f; unsigned u; } c; c.f = x;
    unsigned r = c.u + 0x7fffu + ((c.u >> 16) & 1u);
    return (unsigned short)(r >> 16);
}
__device__ __forceinline__ float bf2f(unsigned short u) {
    union { unsigned u; float f; } c; c.u = ((unsigned)u) << 16;
    return c.f;
}

#define GLDS(g, l) __builtin_amdgcn_global_load_lds( \
    (const __attribute__((address_space(1))) void*)(g), \
    (__attribute__((address_space(3))) void*)(l), 16, 0, 0)

// ---------------------------------------------------------------------------
// MFMA GEMM body: C = act(A(bf16, MxK) @ B^T(bf16, [N][K]) + bias)
// BM=128 BN=64 BK=32, 256 threads = 4 waves (2x2), wave tile 64x32 (4x2 frags)
// 2-phase double-buffered LDS with global_load_lds(16B) staging.
// ---------------------------------------------------------------------------
template<int ACT, int OUT_BF16>   // ACT: 0=relu 1=leaky(0.01); OUT_BF16: 1 -> ushort C
__device__ __forceinline__ void mfma_gemm_body(
    const unsigned short* __restrict__ A, int lda,
    const unsigned short* __restrict__ B, int ldb,   // [N][K] transposed weights
    const float* __restrict__ bias,                  // indexed by global output col
    void* __restrict__ Cout, int ldc, int ccol0,
    int brow, int nbase, int K)
{
    __shared__ unsigned short As[2][128 * 32];  // 8 KB per buf
    __shared__ unsigned short Bs[2][64 * 32];   // 4 KB per buf

    const int t = threadIdx.x;
    const int w = t >> 6;           // wave 0..3
    const int l = t & 63;
    const int lr = l & 15;          // fragment row/col
    const int lk = (l >> 4) << 3;   // fragment k offset: 0,8,16,24
    const int srow = l >> 2;        // staging: row within 16-row chunk
    const int scol = (l & 3) << 3;  // staging: k element offset

    f32x4 acc[4][2];
    #pragma unroll
    for (int m = 0; m < 4; ++m)
        #pragma unroll
        for (int n = 0; n < 2; ++n) acc[m][n] = f32x4{0.f, 0.f, 0.f, 0.f};

    const int nk = K >> 5;

    auto STAGE = [&](int buf, int k0) {
        #pragma unroll
        for (int i = 0; i < 2; ++i) {
            const int c = (w << 1) + i;  // A chunk 0..7 (16 rows each)
            const unsigned short* src = A + (size_t)(brow + c * 16 + srow) * lda + k0 + scol;
            GLDS(src, &As[buf][c * 512]);
        }
        const unsigned short* srcb = B + (size_t)(nbase + w * 16 + srow) * ldb + k0 + scol;
        GLDS(srcb, &Bs[buf][w * 512]);
    };

    STAGE(0, 0);
    asm volatile("s_waitcnt vmcnt(0)" ::: "memory");
    __syncthreads();

    const int wr = w >> 1, wc = w & 1;

    for (int tt = 0; tt < nk; ++tt) {
        const int cur = tt & 1;
        if (tt + 1 < nk) STAGE(cur ^ 1, (tt + 1) << 5);
        bf16x8 af[4], bfr[2];
        #pragma unroll
        for (int m = 0; m < 4; ++m)
            af[m] = *reinterpret_cast<const bf16x8*>(&As[cur][(wr * 64 + m * 16 + lr) * 32 + lk]);
        #pragma unroll
        for (int n = 0; n < 2; ++n)
            bfr[n] = *reinterpret_cast<const bf16x8*>(&Bs[cur][(wc * 32 + n * 16 + lr) * 32 + lk]);
        #pragma unroll
        for (int m = 0; m < 4; ++m)
            #pragma unroll
            for (int n = 0; n < 2; ++n)
                acc[m][n] = __builtin_amdgcn_mfma_f32_16x16x32_bf16(af[m], bfr[n], acc[m][n], 0, 0, 0);
        if (tt + 1 < nk) {
            asm volatile("s_waitcnt vmcnt(0)" ::: "memory");
            __syncthreads();
        }
    }

    // Epilogue: D col = lane&15 (N side), row = (lane>>4)*4 + j (M side)
    const int orow0 = brow + wr * 64 + ((l >> 4) << 2);
    const int ocol0 = ccol0 + wc * 32 + lr;
    #pragma unroll
    for (int m = 0; m < 4; ++m) {
        #pragma unroll
        for (int n = 0; n < 2; ++n) {
            const int col = ocol0 + n * 16;
            const float bz = bias[col];
            #pragma unroll
            for (int j = 0; j < 4; ++j) {
                const int row = orow0 + m * 16 + j;
                float z = acc[m][n][j] + bz;
                if (ACT == 0) z = fmaxf(z, 0.f);
                else          z = (z > 0.f) ? z : 0.01f * z;
                if (OUT_BF16) ((unsigned short*)Cout)[(size_t)row * ldc + col] = f2bf(z);
                else          ((float*)Cout)[(size_t)row * ldc + col] = z;
            }
        }
    }
}

__global__ __launch_bounds__(256) void gemm_top_mfma(
    const unsigned short* __restrict__ dxb, const unsigned short* __restrict__ cxb,
    const unsigned short* __restrict__ WdT, const unsigned short* __restrict__ WcT,
    const float* __restrict__ bd, const float* __restrict__ bc,
    unsigned short* __restrict__ resb)
{
    const int bcol = blockIdx.x * 64;
    const int brow = blockIdx.y * 128;
    if (bcol < 512)
        mfma_gemm_body<0, 1>(dxb, 512, WdT, 512, bd,       resb, 2048, bcol, brow, bcol,       512);
    else
        mfma_gemm_body<0, 1>(cxb, 256, WcT, 256, bc - 512, resb, 2048, bcol, brow, bcol - 512, 256);
}

__global__ __launch_bounds__(256) void gemm_w1_mfma(
    const unsigned short* __restrict__ resb, const unsigned short* __restrict__ W1T,
    const float* __restrict__ b1p, float* __restrict__ h)
{
    mfma_gemm_body<1, 0>(resb, 2048, W1T, 2048, b1p, h, 1024,
                         blockIdx.x * 64, blockIdx.y * 128, blockIdx.x * 64, 2048);
}

// ---------------------------------------------------------------------------
// Prep: bf16 conversions of dx, cx, v; b1 pad; Ve[ch*8+f] = sum_e vb^2
// ---------------------------------------------------------------------------
#define N_DX (2048*512)
#define N_CX (2048*256)
#define N_V  (1017*128)
__global__ __launch_bounds__(256) void prep_misc(
    const float* __restrict__ dx, const float* __restrict__ cx,
    const float* __restrict__ v,  const float* __restrict__ b1,
    unsigned short* __restrict__ dxb, unsigned short* __restrict__ cxb,
    unsigned short* __restrict__ vb, float* __restrict__ b1p, float* __restrict__ Ve)
{
    int i = blockIdx.x * 256 + threadIdx.x;
    const int total = N_DX + N_CX + N_V + 1024 + 8136;
    if (i >= total) return;
    int j = i;
    if (j < N_DX) { dxb[j] = f2bf(dx[j]); return; }
    j -= N_DX;
    if (j < N_CX) { cxb[j] = f2bf(cx[j]); return; }
    j -= N_CX;
    if (j < N_V)  { vb[j] = f2bf(v[j]); return; }
    j -= N_V;
    if (j < 1024) { b1p[j] = (j < 1020) ? b1[j] : 0.f; return; }
    j -= 1024;
    // Ve from bf16-rounded v so FM's two terms cancel consistently
    float s = 0.f;
    const float* vp = v + (size_t)j * 16;
    #pragma unroll
    for (int e = 0; e < 16; ++e) { float vv = bf2f(f2bf(vp[e])); s = fmaf(vv, vv, s); }
    Ve[j] = s;
}

// ---------------------------------------------------------------------------
// Transposes: Wd[512][512]->WdT[512][512], Wc[256][512]->WcT[512][256],
//             W1[2041][1020]->W1T[1024][2048] (zero-padded), all bf16 out.
// ---------------------------------------------------------------------------
__global__ __launch_bounds__(256) void transpose_all(
    const float* __restrict__ Wd, const float* __restrict__ Wc, const float* __restrict__ W1,
    unsigned short* __restrict__ WdT, unsigned short* __restrict__ WcT, unsigned short* __restrict__ W1T)
{
    __shared__ float tile[64][65];
    int bid = blockIdx.x;
    const float* in; unsigned short* out;
    int K0, N0, ldin, Kout, kt, nt;
    if (bid < 64) {
        in = Wd; out = WdT; K0 = 512; N0 = 512; ldin = 512; Kout = 512;
        kt = bid & 7; nt = bid >> 3;
    } else if (bid < 96) {
        bid -= 64;
        in = Wc; out = WcT; K0 = 256; N0 = 512; ldin = 512; Kout = 256;
        kt = bid & 3; nt = bid >> 2;
    } else {
        bid -= 96;
        in = W1; out = W1T; K0 = 2041; N0 = 1020; ldin = 1020; Kout = 2048;
        kt = bid & 31; nt = bid >> 5;
    }
    const int k0 = kt * 64, n0 = nt * 64;
    const int t = threadIdx.x;
    const int nl = t & 63, kq = t >> 6;
    #pragma unroll
    for (int i = 0; i < 16; ++i) {
        const int kl = kq + i * 4;
        const int gk = k0 + kl, gn = n0 + nl;
        tile[kl][nl] = (gk < K0 && gn < N0) ? in[(size_t)gk * ldin + gn] : 0.f;
    }
    __syncthreads();
    const int kl2 = t & 63, nq = t >> 6;
    #pragma unroll
    for (int i = 0; i < 16; ++i) {
        const int nl2 = nq + i * 4;
        out[(size_t)(n0 + nl2) * Kout + k0 + kl2] = f2bf(tile[kl2][nl2]);
    }
}

// ---------------------------------------------------------------------------
// FM: 4 batch rows per block (512 blocks). Per thread: 4 consecutive channels.
// sum_of_sq collapsed via Ve; sq_of_sum accumulated 4 embeddings at a time.
// ---------------------------------------------------------------------------
__global__ __launch_bounds__(256) void fm_kernel(
    const unsigned short* __restrict__ vb, const float* __restrict__ Ve,
    const float* __restrict__ lin_w, const float* __restrict__ lin_b,
    unsigned short* __restrict__ resb)
{
    __shared__ float xs[4][1032];   // 1024 + 8 zero pad
    const int r0 = blockIdx.x * 4;
    const int t  = threadIdx.x;

    #pragma unroll
    for (int r = 0; r < 4; ++r) {
        const ushort4 u = reinterpret_cast<const ushort4*>(resb + (size_t)(r0 + r) * 2048)[t];
        xs[r][t*4+0] = bf2f(u.x); xs[r][t*4+1] = bf2f(u.y);
        xs[r][t*4+2] = bf2f(u.z); xs[r][t*4+3] = bf2f(u.w);
    }
    if (t < 8) {
        #pragma unroll
        for (int r = 0; r < 4; ++r) xs[r][1024 + t] = 0.f;
    }
    __syncthreads();

    float lw[8];
    #pragma unroll
    for (int f = 0; f < 8; ++f) lw[f] = lin_w[f];
    const float lb = lin_b[0];

    const int ch0 = t * 4;
    float xw[4][12];
    #pragma unroll
    for (int r = 0; r < 4; ++r) {
        const float4 a = *reinterpret_cast<const float4*>(&xs[r][ch0]);
        const float4 b = *reinterpret_cast<const float4*>(&xs[r][ch0 + 4]);
        const float4 c = *reinterpret_cast<const float4*>(&xs[r][ch0 + 8]);
        xw[r][0]=a.x; xw[r][1]=a.y; xw[r][2]=a.z; xw[r][3]=a.w;
        xw[r][4]=b.x; xw[r][5]=b.y; xw[r][6]=b.z; xw[r][7]=b.w;
        xw[r][8]=c.x; xw[r][9]=c.y; xw[r][10]=c.z; xw[r][11]=c.w;
    }

    #pragma unroll
    for (int c = 0; c < 4; ++c) {
        const int ch = ch0 + c;
        float outv[4] = {0.f, 0.f, 0.f, 0.f};
        if (ch < 1017) {
            float lin[4], sos[4] = {0,0,0,0}, fmv[4] = {0,0,0,0};
            #pragma unroll
            for (int r = 0; r < 4; ++r) {
                float s = lb;
                #pragma unroll
                for (int f = 0; f < 8; ++f) s = fmaf(xw[r][c+f], lw[f], s);
                lin[r] = s;
            }
            #pragma unroll
            for (int f = 0; f < 8; ++f) {
                const float ve = Ve[ch * 8 + f];
                #pragma unroll
                for (int r = 0; r < 4; ++r)
                    sos[r] = fmaf(xw[r][c+f] * xw[r][c+f], ve, sos[r]);
            }
            const unsigned short* vp = vb + (size_t)ch * 128;
            #pragma unroll
            for (int q = 0; q < 4; ++q) {
                float s[4][4];
                #pragma unroll
                for (int r = 0; r < 4; ++r)
                    #pragma unroll
                    for (int e = 0; e < 4; ++e) s[r][e] = 0.f;
                #pragma unroll
                for (int f = 0; f < 8; ++f) {
                    const ushort4 vv = *reinterpret_cast<const ushort4*>(vp + f * 16 + q * 4);
                    const float v0 = bf2f(vv.x), v1 = bf2f(vv.y), v2 = bf2f(vv.z), v3 = bf2f(vv.w);
                    #pragma unroll
                    for (int r = 0; r < 4; ++r) {
                        const float xf = xw[r][c+f];
                        s[r][0] = fmaf(xf, v0, s[r][0]);
                        s[r][1] = fmaf(xf, v1, s[r][1]);
                        s[r][2] = fmaf(xf, v2, s[r][2]);
                        s[r][3] = fmaf(xf, v3, s[r][3]);
                    }
                }
                #pragma unroll
                for (int r = 0; r < 4; ++r)
                    fmv[r] += s[r][0]*s[r][0] + s[r][1]*s[r][1] + s[r][2]*s[r][2] + s[r][3]*s[r][3];
            }
            #pragma unroll
            for (int r = 0; r < 4; ++r) outv[r] = lin[r] + 0.5f * (fmv[r] - sos[r]);
        }
        #pragma unroll
        for (int r = 0; r < 4; ++r)
            resb[(size_t)(r0 + r) * 2048 + 1024 + ch] = f2bf(outv[r]);
    }
}

// Final: out[b] = sigmoid(dot(h[b,0:1020], W2) + b2)
__global__ __launch_bounds__(256) void final_kernel(
    const float* __restrict__ h, const float* __restrict__ W2,
    const float* __restrict__ b2, float* __restrict__ out)
{
    const int b = blockIdx.x;
    const int t = threadIdx.x;
    float sum = 0.f;
    for (int j = t; j < 1020; j += 256)
        sum = fmaf(h[(size_t)b * 1024 + j], W2[j], sum);
    #pragma unroll
    for (int off = 32; off > 0; off >>= 1)
        sum += __shfl_down(sum, off, 64);
    __shared__ float ps[4];
    if ((t & 63) == 0) ps[t >> 6] = sum;
    __syncthreads();
    if (t == 0) {
        const float z = ps[0] + ps[1] + ps[2] + ps[3] + b2[0];
        out[b] = 1.f / (1.f + expf(-z));
    }
}

extern "C" void kernel_launch(void* const* d_in, const int* in_sizes, int n_in,
                              void* d_out, int out_size, void* d_ws, size_t ws_size,
                              hipStream_t stream)
{
    const float* dx = (const float*)d_in[0];
    const float* cx = (const float*)d_in[1];
    const float* Wd = (const float*)d_in[2];
    const float* bd = (const float*)d_in[3];
    const float* Wc = (const float*)d_in[4];
    const float* bc = (const float*)d_in[5];
    const float* v  = (const float*)d_in[6];
    const float* lw = (const float*)d_in[7];
    const float* lb = (const float*)d_in[8];
    const float* W1 = (const float*)d_in[9];
    const float* b1 = (const float*)d_in[10];
    const float* W2 = (const float*)d_in[11];
    const float* b2 = (const float*)d_in[12];
    float* out = (float*)d_out;

    char* ws = (char*)d_ws;
    unsigned short* resb = (unsigned short*)(ws);                       // 8 MB
    float*          h    = (float*)(ws + (8u  << 20));                  // 8 MB
    unsigned short* dxb  = (unsigned short*)(ws + (16u << 20));         // 2 MB
    unsigned short* cxb  = (unsigned short*)(ws + (18u << 20));         // 1 MB
    unsigned short* WdT  = (unsigned short*)(ws + (19u << 20));         // 512 KB
    unsigned short* WcT  = (unsigned short*)(ws + (19u << 20) + (512u << 10)); // 256 KB
    unsigned short* W1T  = (unsigned short*)(ws + (20u << 20));         // 4 MB
    unsigned short* vb   = (unsigned short*)(ws + (24u << 20));         // 255 KB
    float*          Ve   = (float*)(ws + (24u << 20) + (320u << 10));   // 32 KB
    float*          b1p  = (float*)(ws + (24u << 20) + (384u << 10));   // 4 KB

    const int prep_total = N_DX + N_CX + N_V + 1024 + 8136;
    hipLaunchKernelGGL(prep_misc, dim3((prep_total + 255) / 256), dim3(256), 0, stream,
                       dx, cx, v, b1, dxb, cxb, vb, b1p, Ve);
    hipLaunchKernelGGL(transpose_all, dim3(608), dim3(256), 0, stream,
                       Wd, Wc, W1, WdT, WcT, W1T);
    hipLaunchKernelGGL(gemm_top_mfma, dim3(16, 16), dim3(256), 0, stream,
                       dxb, cxb, WdT, WcT, bd, bc, resb);
    hipLaunchKernelGGL(fm_kernel, dim3(512), dim3(256), 0, stream,
                       vb, Ve, lw, lb, resb);
    hipLaunchKernelGGL(gemm_w1_mfma, dim3(16, 16), dim3(256), 0, stream,
                       resb, W1T, b1p, h);
    hipLaunchKernelGGL(final_kernel, dim3(2048), dim3(256), 0, stream,
                       h, W2, b2, out);
}

// Round 3
// 85.874 us; speedup vs baseline: 4.0948x; 1.0841x over previous
//
#include <hip/hip_runtime.h>
#include <math.h>

// NDF=512 NCF=256 NCC=256 EMB=16 FIELD=8 B=2048
// NH0=1024 CHANNEL=1017 HID=1020 K3=2041
// resb: [2048][2048] bf16 (cols 0..1023 = x, 1024..2040 = x_fm2, 2041..2047 = 0)

typedef __bf16 bf16x8 __attribute__((ext_vector_type(8)));
typedef float  f32x4  __attribute__((ext_vector_type(4)));

__device__ __forceinline__ unsigned short f2bf(float x) {
    union { float f; unsigned u; } c; c.f = x;
    unsigned r = c.u + 0x7fffu + ((c.u >> 16) & 1u);
    return (unsigned short)(r >> 16);
}
__device__ __forceinline__ float bf2f(unsigned short u) {
    union { unsigned u; float f; } c; c.u = ((unsigned)u) << 16;
    return c.f;
}

#define GLDS(g, l) __builtin_amdgcn_global_load_lds( \
    (const __attribute__((address_space(1))) void*)(g), \
    (__attribute__((address_space(3))) void*)(l), 16, 0, 0)

// ---------------------------------------------------------------------------
// MFMA GEMM: C = act(A(bf16,MxK) @ B^T(bf16,[N][K]) + bias)
// BM=128 BN=32 BK=64, 512 threads (8 waves, 4x2), wave tile 32x16.
// 3-buffer LDS pipeline, counted vmcnt, 1 raw barrier/K-step.
// LDS rows are 128B, XOR-swizzled (byte ^= (row&7)<<4) via pre-swizzled
// global source for global_load_lds + same XOR on ds_read (rule #21).
// ---------------------------------------------------------------------------
template<int ACT, int FUSE>   // ACT 0=relu 1=leaky; FUSE 1 = dot-W2 epilogue
__device__ __forceinline__ void mfma_gemm_body(
    const unsigned short* __restrict__ A, int lda,
    const unsigned short* __restrict__ B, int ldb,
    const float* __restrict__ bias,
    unsigned short* __restrict__ Cb, int ldc,          // FUSE=0
    const float* __restrict__ W2p, float* __restrict__ part, // FUSE=1
    int ccol0, int brow, int nbase, int K, int cbwc_base)
{
    __shared__ __align__(128) unsigned short As[3][128 * 64];  // 16KB x3
    __shared__ __align__(128) unsigned short Bs[3][32 * 64];   // 4KB x3

    const int t = threadIdx.x;
    const int w = t >> 6;
    const int l = t & 63;
    const int lr = l & 15, hi = l >> 4;
    const int g = l & 7, s8 = l >> 3;
    const int scol = ((g ^ s8) << 3);     // pre-swizzled k-element offset
    const int wr = w >> 1, wc = w & 1;
    const bool hasB = (w < 4);

    f32x4 acc[2];
    acc[0] = f32x4{0.f,0.f,0.f,0.f};
    acc[1] = f32x4{0.f,0.f,0.f,0.f};

    const int nk = K >> 6;

    auto STAGE = [&](int buf, int k0) {
        const unsigned short* sa0 = A + (size_t)(brow + w * 16 + s8) * lda + k0 + scol;
        GLDS(sa0, &As[buf][(w * 16) * 64]);
        const unsigned short* sa1 = A + (size_t)(brow + w * 16 + 8 + s8) * lda + k0 + scol;
        GLDS(sa1, &As[buf][(w * 16 + 8) * 64]);
        if (hasB) {
            const unsigned short* sb = B + (size_t)(nbase + w * 8 + s8) * ldb + k0 + scol;
            GLDS(sb, &Bs[buf][(w * 8) * 64]);
        }
    };

    STAGE(0, 0);
    if (nk > 1) STAGE(1, 64);

    for (int tt = 0; tt < nk; ++tt) {
        // counted wait: newest stages (t+1, if issued) may stay in flight
        if (tt < nk - 1) {
            if (hasB) asm volatile("s_waitcnt vmcnt(3)" ::: "memory");
            else      asm volatile("s_waitcnt vmcnt(2)" ::: "memory");
        } else {
            asm volatile("s_waitcnt vmcnt(0)" ::: "memory");
        }
        __builtin_amdgcn_s_barrier();
        if (tt + 2 < nk) STAGE((tt + 2) % 3, (tt + 2) << 6);

        const char* pa = (const char*)&As[tt % 3][0];
        const char* pb = (const char*)&Bs[tt % 3][0];
        const int xo = (lr & 7) << 4;
        bf16x8 af[2][2], bfv[2];
        #pragma unroll
        for (int m = 0; m < 2; ++m) {
            const int row = wr * 32 + m * 16 + lr;
            #pragma unroll
            for (int ks = 0; ks < 2; ++ks)
                af[m][ks] = *(const bf16x8*)(pa + row * 128 + (((ks << 6) + (hi << 4)) ^ xo));
        }
        {
            const int rowb = wc * 16 + lr;
            #pragma unroll
            for (int ks = 0; ks < 2; ++ks)
                bfv[ks] = *(const bf16x8*)(pb + rowb * 128 + (((ks << 6) + (hi << 4)) ^ xo));
        }
        #pragma unroll
        for (int ks = 0; ks < 2; ++ks)
            #pragma unroll
            for (int m = 0; m < 2; ++m)
                acc[m] = __builtin_amdgcn_mfma_f32_16x16x32_bf16(af[m][ks], bfv[ks], acc[m], 0, 0, 0);
    }

    // Epilogue. C/D map: col = lane&15, row = (lane>>4)*4 + j.
    const int orow0 = brow + wr * 32 + hi * 4;
    const int col = ccol0 + wc * 16 + lr;
    const float bz = bias[col];
    if (FUSE) {
        const float w2 = W2p[col];
        #pragma unroll
        for (int m = 0; m < 2; ++m) {
            #pragma unroll
            for (int j = 0; j < 4; ++j) {
                float z = acc[m][j] + bz;
                z = (z > 0.f) ? z : 0.01f * z;
                float p = z * w2;
                p += __shfl_xor(p, 1, 64);
                p += __shfl_xor(p, 2, 64);
                p += __shfl_xor(p, 4, 64);
                p += __shfl_xor(p, 8, 64);
                if (lr == 0)
                    part[(size_t)(cbwc_base + wc) * 2048 + orow0 + m * 16 + j] = p;
            }
        }
    } else {
        #pragma unroll
        for (int m = 0; m < 2; ++m) {
            #pragma unroll
            for (int j = 0; j < 4; ++j) {
                float z = acc[m][j] + bz;
                z = fmaxf(z, 0.f);
                Cb[(size_t)(orow0 + m * 16 + j) * ldc + col] = f2bf(z);
            }
        }
    }
}

__global__ __launch_bounds__(512) void gemm_top_mfma(
    const unsigned short* __restrict__ dxb, const unsigned short* __restrict__ cxb,
    const unsigned short* __restrict__ WdT, const unsigned short* __restrict__ WcT,
    const float* __restrict__ bd, const float* __restrict__ bc,
    unsigned short* __restrict__ resb)
{
    const int cb = blockIdx.x;          // 0..31
    const int brow = blockIdx.y * 128;
    const int ccol0 = cb * 32;
    if (cb < 16)
        mfma_gemm_body<0, 0>(dxb, 512, WdT, 512, bd, resb, 2048,
                             nullptr, nullptr, ccol0, brow, ccol0, 512, 0);
    else
        mfma_gemm_body<0, 0>(cxb, 256, WcT, 256, bc - 512, resb, 2048,
                             nullptr, nullptr, ccol0, brow, ccol0 - 512, 256, 0);
}

__global__ __launch_bounds__(512) void gemm_w1_mfma(
    const unsigned short* __restrict__ resb, const unsigned short* __restrict__ W1T,
    const float* __restrict__ b1p, const float* __restrict__ W2p,
    float* __restrict__ part)
{
    const int cb = blockIdx.x;          // 0..31
    mfma_gemm_body<1, 1>(resb, 2048, W1T, 2048, b1p, nullptr, 0,
                         W2p, part, cb * 32, blockIdx.y * 128, cb * 32, 2048, cb * 2);
}

// ---------------------------------------------------------------------------
#define N_DX (2048*512)
#define N_CX (2048*256)
#define N_V  (1017*128)
__global__ __launch_bounds__(256) void prep_misc(
    const float* __restrict__ dx, const float* __restrict__ cx,
    const float* __restrict__ v,  const float* __restrict__ b1,
    const float* __restrict__ W2,
    unsigned short* __restrict__ dxb, unsigned short* __restrict__ cxb,
    unsigned short* __restrict__ vb, float* __restrict__ b1p,
    float* __restrict__ W2p, float* __restrict__ Ve)
{
    int i = blockIdx.x * 256 + threadIdx.x;
    int j = i;
    if (j < N_DX) { dxb[j] = f2bf(dx[j]); return; }
    j -= N_DX;
    if (j < N_CX) { cxb[j] = f2bf(cx[j]); return; }
    j -= N_CX;
    if (j < N_V)  { vb[j] = f2bf(v[j]); return; }
    j -= N_V;
    if (j < 1024) { b1p[j] = (j < 1020) ? b1[j] : 0.f; return; }
    j -= 1024;
    if (j < 1024) { W2p[j] = (j < 1020) ? W2[j] : 0.f; return; }
    j -= 1024;
    if (j >= 8136) return;
    float s = 0.f;
    const float* vp = v + (size_t)j * 16;
    #pragma unroll
    for (int e = 0; e < 16; ++e) { float vv = bf2f(f2bf(vp[e])); s = fmaf(vv, vv, s); }
    Ve[j] = s;
}

__global__ __launch_bounds__(256) void transpose_all(
    const float* __restrict__ Wd, const float* __restrict__ Wc, const float* __restrict__ W1,
    unsigned short* __restrict__ WdT, unsigned short* __restrict__ WcT, unsigned short* __restrict__ W1T)
{
    __shared__ float tile[64][65];
    int bid = blockIdx.x;
    const float* in; unsigned short* out;
    int K0, N0, ldin, Kout, kt, nt;
    if (bid < 64) {
        in = Wd; out = WdT; K0 = 512; N0 = 512; ldin = 512; Kout = 512;
        kt = bid & 7; nt = bid >> 3;
    } else if (bid < 96) {
        bid -= 64;
        in = Wc; out = WcT; K0 = 256; N0 = 512; ldin = 512; Kout = 256;
        kt = bid & 3; nt = bid >> 2;
    } else {
        bid -= 96;
        in = W1; out = W1T; K0 = 2041; N0 = 1020; ldin = 1020; Kout = 2048;
        kt = bid & 31; nt = bid >> 5;
    }
    const int k0 = kt * 64, n0 = nt * 64;
    const int t = threadIdx.x;
    const int nl = t & 63, kq = t >> 6;
    #pragma unroll
    for (int i = 0; i < 16; ++i) {
        const int kl = kq + i * 4;
        const int gk = k0 + kl, gn = n0 + nl;
        tile[kl][nl] = (gk < K0 && gn < N0) ? in[(size_t)gk * ldin + gn] : 0.f;
    }
    __syncthreads();
    const int kl2 = t & 63, nq = t >> 6;
    #pragma unroll
    for (int i = 0; i < 16; ++i) {
        const int nl2 = nq + i * 4;
        out[(size_t)(n0 + nl2) * Kout + k0 + kl2] = f2bf(tile[kl2][nl2]);
    }
}

// ---------------------------------------------------------------------------
// FM: 4 batch rows/block (512 blocks), thread: 4 consecutive channels.
// ---------------------------------------------------------------------------
__global__ __launch_bounds__(256) void fm_kernel(
    const unsigned short* __restrict__ vb, const float* __restrict__ Ve,
    const float* __restrict__ lin_w, const float* __restrict__ lin_b,
    unsigned short* __restrict__ resb)
{
    __shared__ float xs[4][1032];
    const int r0 = blockIdx.x * 4;
    const int t  = threadIdx.x;

    #pragma unroll
    for (int r = 0; r < 4; ++r) {
        const ushort4 u = reinterpret_cast<const ushort4*>(resb + (size_t)(r0 + r) * 2048)[t];
        xs[r][t*4+0] = bf2f(u.x); xs[r][t*4+1] = bf2f(u.y);
        xs[r][t*4+2] = bf2f(u.z); xs[r][t*4+3] = bf2f(u.w);
    }
    if (t < 8) {
        #pragma unroll
        for (int r = 0; r < 4; ++r) xs[r][1024 + t] = 0.f;
    }
    __syncthreads();

    float lw[8];
    #pragma unroll
    for (int f = 0; f < 8; ++f) lw[f] = lin_w[f];
    const float lb = lin_b[0];

    const int ch0 = t * 4;
    float xw[4][12];
    #pragma unroll
    for (int r = 0; r < 4; ++r) {
        const float4 a = *reinterpret_cast<const float4*>(&xs[r][ch0]);
        const float4 b = *reinterpret_cast<const float4*>(&xs[r][ch0 + 4]);
        const float4 c = *reinterpret_cast<const float4*>(&xs[r][ch0 + 8]);
        xw[r][0]=a.x; xw[r][1]=a.y; xw[r][2]=a.z; xw[r][3]=a.w;
        xw[r][4]=b.x; xw[r][5]=b.y; xw[r][6]=b.z; xw[r][7]=b.w;
        xw[r][8]=c.x; xw[r][9]=c.y; xw[r][10]=c.z; xw[r][11]=c.w;
    }

    #pragma unroll
    for (int c = 0; c < 4; ++c) {
        const int ch = ch0 + c;
        float outv[4] = {0.f, 0.f, 0.f, 0.f};
        if (ch < 1017) {
            float lin[4], sos[4] = {0,0,0,0}, fmv[4] = {0,0,0,0};
            #pragma unroll
            for (int r = 0; r < 4; ++r) {
                float s = lb;
                #pragma unroll
                for (int f = 0; f < 8; ++f) s = fmaf(xw[r][c+f], lw[f], s);
                lin[r] = s;
            }
            #pragma unroll
            for (int f = 0; f < 8; ++f) {
                const float ve = Ve[ch * 8 + f];
                #pragma unroll
                for (int r = 0; r < 4; ++r)
                    sos[r] = fmaf(xw[r][c+f] * xw[r][c+f], ve, sos[r]);
            }
            const unsigned short* vp = vb + (size_t)ch * 128;
            #pragma unroll
            for (int q = 0; q < 4; ++q) {
                float s[4][4];
                #pragma unroll
                for (int r = 0; r < 4; ++r)
                    #pragma unroll
                    for (int e = 0; e < 4; ++e) s[r][e] = 0.f;
                #pragma unroll
                for (int f = 0; f < 8; ++f) {
                    const ushort4 vv = *reinterpret_cast<const ushort4*>(vp + f * 16 + q * 4);
                    const float v0 = bf2f(vv.x), v1 = bf2f(vv.y), v2 = bf2f(vv.z), v3 = bf2f(vv.w);
                    #pragma unroll
                    for (int r = 0; r < 4; ++r) {
                        const float xf = xw[r][c+f];
                        s[r][0] = fmaf(xf, v0, s[r][0]);
                        s[r][1] = fmaf(xf, v1, s[r][1]);
                        s[r][2] = fmaf(xf, v2, s[r][2]);
                        s[r][3] = fmaf(xf, v3, s[r][3]);
                    }
                }
                #pragma unroll
                for (int r = 0; r < 4; ++r)
                    fmv[r] += s[r][0]*s[r][0] + s[r][1]*s[r][1] + s[r][2]*s[r][2] + s[r][3]*s[r][3];
            }
            #pragma unroll
            for (int r = 0; r < 4; ++r) outv[r] = lin[r] + 0.5f * (fmv[r] - sos[r]);
        }
        #pragma unroll
        for (int r = 0; r < 4; ++r)
            resb[(size_t)(r0 + r) * 2048 + 1024 + ch] = f2bf(outv[r]);
    }
}

// Final: out[b] = sigmoid(sum_{i<64} part[i][b] + b2)
__global__ __launch_bounds__(256) void final2_kernel(
    const float* __restrict__ part, const float* __restrict__ b2,
    float* __restrict__ out)
{
    const int b = blockIdx.x * 256 + threadIdx.x;
    float s = b2[0];
    #pragma unroll
    for (int i = 0; i < 64; ++i) s += part[(size_t)i * 2048 + b];
    out[b] = 1.f / (1.f + expf(-s));
}

extern "C" void kernel_launch(void* const* d_in, const int* in_sizes, int n_in,
                              void* d_out, int out_size, void* d_ws, size_t ws_size,
                              hipStream_t stream)
{
    const float* dx = (const float*)d_in[0];
    const float* cx = (const float*)d_in[1];
    const float* Wd = (const float*)d_in[2];
    const float* bd = (const float*)d_in[3];
    const float* Wc = (const float*)d_in[4];
    const float* bc = (const float*)d_in[5];
    const float* v  = (const float*)d_in[6];
    const float* lw = (const float*)d_in[7];
    const float* lb = (const float*)d_in[8];
    const float* W1 = (const float*)d_in[9];
    const float* b1 = (const float*)d_in[10];
    const float* W2 = (const float*)d_in[11];
    const float* b2 = (const float*)d_in[12];
    float* out = (float*)d_out;

    char* ws = (char*)d_ws;
    unsigned short* resb = (unsigned short*)(ws);                              // 8 MB
    float*          part = (float*)(ws + (8u << 20));                          // 512 KB
    unsigned short* dxb  = (unsigned short*)(ws + (9u << 20));                 // 2 MB
    unsigned short* cxb  = (unsigned short*)(ws + (11u << 20));                // 1 MB
    unsigned short* WdT  = (unsigned short*)(ws + (12u << 20));                // 512 KB
    unsigned short* WcT  = (unsigned short*)(ws + (12u << 20) + (512u << 10)); // 256 KB
    unsigned short* W1T  = (unsigned short*)(ws + (13u << 20));                // 4 MB
    unsigned short* vb   = (unsigned short*)(ws + (17u << 20));                // 255 KB
    float*          Ve   = (float*)(ws + (17u << 20) + (320u << 10));          // 32 KB
    float*          b1p  = (float*)(ws + (17u << 20) + (384u << 10));          // 4 KB
    float*          W2p  = (float*)(ws + (17u << 20) + (388u << 10));          // 4 KB

    const int prep_total = N_DX + N_CX + N_V + 1024 + 1024 + 8136;
    hipLaunchKernelGGL(prep_misc, dim3((prep_total + 255) / 256), dim3(256), 0, stream,
                       dx, cx, v, b1, W2, dxb, cxb, vb, b1p, W2p, Ve);
    hipLaunchKernelGGL(transpose_all, dim3(608), dim3(256), 0, stream,
                       Wd, Wc, W1, WdT, WcT, W1T);
    hipLaunchKernelGGL(gemm_top_mfma, dim3(32, 16), dim3(512), 0, stream,
                       dxb, cxb, WdT, WcT, bd, bc, resb);
    hipLaunchKernelGGL(fm_kernel, dim3(512), dim3(256), 0, stream,
                       vb, Ve, lw, lb, resb);
    hipLaunchKernelGGL(gemm_w1_mfma, dim3(32, 16), dim3(512), 0, stream,
                       resb, W1T, b1p, W2p, part);
    hipLaunchKernelGGL(final2_kernel, dim3(8), dim3(256), 0, stream,
                       part, b2, out);
}

// Round 4
// 68.074 us; speedup vs baseline: 5.1656x; 1.2615x over previous
//
#include <hip/hip_runtime.h>
#include <math.h>

// NDF=512 NCF=256 NCC=256 EMB=16 FIELD=8 B=2048
// NH0=1024 CHANNEL=1017 HID=1020 K3=2041
// resb: [2048][2048] bf16 (cols 0..1023 = x, 1024..2040 = x_fm2, 2041..2047 = 0)

typedef __bf16 bf16x8 __attribute__((ext_vector_type(8)));
typedef float  f32x4  __attribute__((ext_vector_type(4)));

__device__ __forceinline__ unsigned short f2bf(float x) {
    union { float f; unsigned u; } c; c.f = x;
    unsigned r = c.u + 0x7fffu + ((c.u >> 16) & 1u);
    return (unsigned short)(r >> 16);
}
__device__ __forceinline__ float bf2f(unsigned short u) {
    union { unsigned u; float f; } c; c.u = ((unsigned)u) << 16;
    return c.f;
}

#define GLDS(g, l) __builtin_amdgcn_global_load_lds( \
    (const __attribute__((address_space(1))) void*)(g), \
    (__attribute__((address_space(3))) void*)(l), 16, 0, 0)

// ---------------------------------------------------------------------------
// MFMA GEMM: C = act(A(bf16,MxK) @ B^T(bf16,[N][K]) + bias)
// BM=128 BN=64 BK=64, 512 threads (8 waves, 4x2 grid), wave tile 32x32.
// 3-buffer LDS pipeline, counted vmcnt(3), 1 raw barrier/K-step.
// LDS rows 128B, XOR-swizzle byte ^= (row&7)<<4 applied on BOTH sides:
// pre-swizzled global source for global_load_lds + same XOR on ds_read.
// ---------------------------------------------------------------------------
template<int ACT, int FUSE>   // ACT 0=relu 1=leaky; FUSE 1 = dot-W2 epilogue
__device__ __forceinline__ void mfma_gemm_body(
    const unsigned short* __restrict__ A, int lda,
    const unsigned short* __restrict__ B, int ldb,
    const float* __restrict__ bias,
    unsigned short* __restrict__ Cb, int ldc,                 // FUSE=0
    const float* __restrict__ W2p, float* __restrict__ part,  // FUSE=1
    int ccol0, int brow, int nbase, int K, int pcolb)
{
    __shared__ __align__(128) unsigned short As[3][128 * 64];  // 16KB x3
    __shared__ __align__(128) unsigned short Bs[3][64 * 64];   // 8KB x3

    const int t = threadIdx.x;
    const int w = t >> 6;
    const int l = t & 63;
    const int lr = l & 15, hi = l >> 4;
    const int g = l & 7, s8 = l >> 3;
    const int scol = ((g ^ s8) << 3);     // pre-swizzled k-element offset
    const int wr = w >> 1, wc = w & 1;    // wave tile: rows wr*32, cols wc*32

    f32x4 acc[2][2];
    #pragma unroll
    for (int m = 0; m < 2; ++m)
        #pragma unroll
        for (int n = 0; n < 2; ++n) acc[m][n] = f32x4{0.f,0.f,0.f,0.f};

    const int nk = K >> 6;

    auto STAGE = [&](int buf, int k0) {
        const unsigned short* sa0 = A + (size_t)(brow + w * 16 + s8) * lda + k0 + scol;
        GLDS(sa0, &As[buf][(w * 16) * 64]);
        const unsigned short* sa1 = A + (size_t)(brow + w * 16 + 8 + s8) * lda + k0 + scol;
        GLDS(sa1, &As[buf][(w * 16 + 8) * 64]);
        const unsigned short* sb = B + (size_t)(nbase + w * 8 + s8) * ldb + k0 + scol;
        GLDS(sb, &Bs[buf][(w * 8) * 64]);
    };

    STAGE(0, 0);
    if (nk > 1) STAGE(1, 64);

    for (int tt = 0; tt < nk; ++tt) {
        if (tt < nk - 1) asm volatile("s_waitcnt vmcnt(3)" ::: "memory");
        else             asm volatile("s_waitcnt vmcnt(0)" ::: "memory");
        __builtin_amdgcn_s_barrier();
        if (tt + 2 < nk) STAGE((tt + 2) % 3, (tt + 2) << 6);

        const char* pa = (const char*)&As[tt % 3][0];
        const char* pb = (const char*)&Bs[tt % 3][0];
        const int xo = (lr & 7) << 4;
        bf16x8 af[2][2], bfv[2][2];
        #pragma unroll
        for (int m = 0; m < 2; ++m) {
            const int row = wr * 32 + m * 16 + lr;
            #pragma unroll
            for (int ks = 0; ks < 2; ++ks)
                af[m][ks] = *(const bf16x8*)(pa + row * 128 + (((ks << 6) | (hi << 4)) ^ xo));
        }
        #pragma unroll
        for (int n = 0; n < 2; ++n) {
            const int rowb = wc * 32 + n * 16 + lr;
            #pragma unroll
            for (int ks = 0; ks < 2; ++ks)
                bfv[n][ks] = *(const bf16x8*)(pb + rowb * 128 + (((ks << 6) | (hi << 4)) ^ xo));
        }
        #pragma unroll
        for (int ks = 0; ks < 2; ++ks)
            #pragma unroll
            for (int m = 0; m < 2; ++m)
                #pragma unroll
                for (int n = 0; n < 2; ++n)
                    acc[m][n] = __builtin_amdgcn_mfma_f32_16x16x32_bf16(af[m][ks], bfv[n][ks], acc[m][n], 0, 0, 0);
    }

    // Epilogue. C/D map: col = lane&15, row = (lane>>4)*4 + j.
    const int orow0 = brow + wr * 32 + hi * 4;
    if (FUSE) {
        float bz[2], w2v[2];
        #pragma unroll
        for (int n = 0; n < 2; ++n) {
            const int col = ccol0 + wc * 32 + n * 16 + lr;
            bz[n] = bias[col];
            w2v[n] = W2p[col];
        }
        #pragma unroll
        for (int m = 0; m < 2; ++m) {
            #pragma unroll
            for (int j = 0; j < 4; ++j) {
                float p = 0.f;
                #pragma unroll
                for (int n = 0; n < 2; ++n) {
                    float z = acc[m][n][j] + bz[n];
                    z = (z > 0.f) ? z : 0.01f * z;
                    p = fmaf(z, w2v[n], p);
                }
                p += __shfl_xor(p, 1, 64);
                p += __shfl_xor(p, 2, 64);
                p += __shfl_xor(p, 4, 64);
                p += __shfl_xor(p, 8, 64);
                if (lr == 0)
                    part[(size_t)(pcolb + wc) * 2048 + orow0 + m * 16 + j] = p;
            }
        }
    } else {
        #pragma unroll
        for (int m = 0; m < 2; ++m) {
            #pragma unroll
            for (int n = 0; n < 2; ++n) {
                const int col = ccol0 + wc * 32 + n * 16 + lr;
                const float bz = bias[col];
                #pragma unroll
                for (int j = 0; j < 4; ++j) {
                    float z = acc[m][n][j] + bz;
                    z = fmaxf(z, 0.f);
                    Cb[(size_t)(orow0 + m * 16 + j) * ldc + col] = f2bf(z);
                }
            }
        }
    }
}

__global__ __launch_bounds__(512) void gemm_top_mfma(
    const unsigned short* __restrict__ dxb, const unsigned short* __restrict__ cxb,
    const unsigned short* __restrict__ WdT, const unsigned short* __restrict__ WcT,
    const float* __restrict__ bd, const float* __restrict__ bc,
    unsigned short* __restrict__ resb)
{
    const int bid = blockIdx.x;                   // 256 blocks
    const int swz = (bid & 7) * 32 + (bid >> 3);  // bijective XCD swizzle
    const int cb = swz & 15;                      // col block (64 cols)
    const int brow = (swz >> 4) * 128;
    const int ccol0 = cb * 64;
    if (cb < 8)
        mfma_gemm_body<0, 0>(dxb, 512, WdT, 512, bd, resb, 2048,
                             nullptr, nullptr, ccol0, brow, ccol0, 512, 0);
    else
        mfma_gemm_body<0, 0>(cxb, 256, WcT, 256, bc - 512, resb, 2048,
                             nullptr, nullptr, ccol0, brow, ccol0 - 512, 256, 0);
}

__global__ __launch_bounds__(512) void gemm_w1_mfma(
    const unsigned short* __restrict__ resb, const unsigned short* __restrict__ W1T,
    const float* __restrict__ b1p, const float* __restrict__ W2p,
    float* __restrict__ part)
{
    const int bid = blockIdx.x;                   // 256 blocks
    const int swz = (bid & 7) * 32 + (bid >> 3);
    const int cb = swz & 15;
    const int brow = (swz >> 4) * 128;
    mfma_gemm_body<1, 1>(resb, 2048, W1T, 2048, b1p, nullptr, 0,
                         W2p, part, cb * 64, brow, cb * 64, 2048, cb * 2);
}

// ---------------------------------------------------------------------------
#define N_DX (2048*512)
#define N_CX (2048*256)
#define N_V  (1017*128)
__global__ __launch_bounds__(256) void prep_misc(
    const float* __restrict__ dx, const float* __restrict__ cx,
    const float* __restrict__ v,  const float* __restrict__ b1,
    const float* __restrict__ W2,
    unsigned short* __restrict__ dxb, unsigned short* __restrict__ cxb,
    unsigned short* __restrict__ vb, float* __restrict__ b1p,
    float* __restrict__ W2p, float* __restrict__ Ve)
{
    int i = blockIdx.x * 256 + threadIdx.x;
    int j = i;
    if (j < N_DX) { dxb[j] = f2bf(dx[j]); return; }
    j -= N_DX;
    if (j < N_CX) { cxb[j] = f2bf(cx[j]); return; }
    j -= N_CX;
    if (j < N_V)  { vb[j] = f2bf(v[j]); return; }
    j -= N_V;
    if (j < 1024) { b1p[j] = (j < 1020) ? b1[j] : 0.f; return; }
    j -= 1024;
    if (j < 1024) { W2p[j] = (j < 1020) ? W2[j] : 0.f; return; }
    j -= 1024;
    if (j >= 8136) return;
    float s = 0.f;
    const float* vp = v + (size_t)j * 16;
    #pragma unroll
    for (int e = 0; e < 16; ++e) { float vv = bf2f(f2bf(vp[e])); s = fmaf(vv, vv, s); }
    Ve[j] = s;
}

__global__ __launch_bounds__(256) void transpose_all(
    const float* __restrict__ Wd, const float* __restrict__ Wc, const float* __restrict__ W1,
    unsigned short* __restrict__ WdT, unsigned short* __restrict__ WcT, unsigned short* __restrict__ W1T)
{
    __shared__ float tile[64][65];
    int bid = blockIdx.x;
    const float* in; unsigned short* out;
    int K0, N0, ldin, Kout, kt, nt;
    if (bid < 64) {
        in = Wd; out = WdT; K0 = 512; N0 = 512; ldin = 512; Kout = 512;
        kt = bid & 7; nt = bid >> 3;
    } else if (bid < 96) {
        bid -= 64;
        in = Wc; out = WcT; K0 = 256; N0 = 512; ldin = 512; Kout = 256;
        kt = bid & 3; nt = bid >> 2;
    } else {
        bid -= 96;
        in = W1; out = W1T; K0 = 2041; N0 = 1020; ldin = 1020; Kout = 2048;
        kt = bid & 31; nt = bid >> 5;
    }
    const int k0 = kt * 64, n0 = nt * 64;
    const int t = threadIdx.x;
    const int nl = t & 63, kq = t >> 6;
    #pragma unroll
    for (int i = 0; i < 16; ++i) {
        const int kl = kq + i * 4;
        const int gk = k0 + kl, gn = n0 + nl;
        tile[kl][nl] = (gk < K0 && gn < N0) ? in[(size_t)gk * ldin + gn] : 0.f;
    }
    __syncthreads();
    const int kl2 = t & 63, nq = t >> 6;
    #pragma unroll
    for (int i = 0; i < 16; ++i) {
        const int nl2 = nq + i * 4;
        out[(size_t)(n0 + nl2) * Kout + k0 + kl2] = f2bf(tile[kl2][nl2]);
    }
}

// ---------------------------------------------------------------------------
// FM: 4 batch rows/block (512 blocks), thread: 4 consecutive channels.
// ---------------------------------------------------------------------------
__global__ __launch_bounds__(256) void fm_kernel(
    const unsigned short* __restrict__ vb, const float* __restrict__ Ve,
    const float* __restrict__ lin_w, const float* __restrict__ lin_b,
    unsigned short* __restrict__ resb)
{
    __shared__ float xs[4][1032];
    const int r0 = blockIdx.x * 4;
    const int t  = threadIdx.x;

    #pragma unroll
    for (int r = 0; r < 4; ++r) {
        const ushort4 u = reinterpret_cast<const ushort4*>(resb + (size_t)(r0 + r) * 2048)[t];
        xs[r][t*4+0] = bf2f(u.x); xs[r][t*4+1] = bf2f(u.y);
        xs[r][t*4+2] = bf2f(u.z); xs[r][t*4+3] = bf2f(u.w);
    }
    if (t < 8) {
        #pragma unroll
        for (int r = 0; r < 4; ++r) xs[r][1024 + t] = 0.f;
    }
    __syncthreads();

    float lw[8];
    #pragma unroll
    for (int f = 0; f < 8; ++f) lw[f] = lin_w[f];
    const float lb = lin_b[0];

    const int ch0 = t * 4;
    float xw[4][12];
    #pragma unroll
    for (int r = 0; r < 4; ++r) {
        const float4 a = *reinterpret_cast<const float4*>(&xs[r][ch0]);
        const float4 b = *reinterpret_cast<const float4*>(&xs[r][ch0 + 4]);
        const float4 c = *reinterpret_cast<const float4*>(&xs[r][ch0 + 8]);
        xw[r][0]=a.x; xw[r][1]=a.y; xw[r][2]=a.z; xw[r][3]=a.w;
        xw[r][4]=b.x; xw[r][5]=b.y; xw[r][6]=b.z; xw[r][7]=b.w;
        xw[r][8]=c.x; xw[r][9]=c.y; xw[r][10]=c.z; xw[r][11]=c.w;
    }

    #pragma unroll
    for (int c = 0; c < 4; ++c) {
        const int ch = ch0 + c;
        float outv[4] = {0.f, 0.f, 0.f, 0.f};
        if (ch < 1017) {
            float lin[4], sos[4] = {0,0,0,0}, fmv[4] = {0,0,0,0};
            #pragma unroll
            for (int r = 0; r < 4; ++r) {
                float s = lb;
                #pragma unroll
                for (int f = 0; f < 8; ++f) s = fmaf(xw[r][c+f], lw[f], s);
                lin[r] = s;
            }
            #pragma unroll
            for (int f = 0; f < 8; ++f) {
                const float ve = Ve[ch * 8 + f];
                #pragma unroll
                for (int r = 0; r < 4; ++r)
                    sos[r] = fmaf(xw[r][c+f] * xw[r][c+f], ve, sos[r]);
            }
            const unsigned short* vp = vb + (size_t)ch * 128;
            #pragma unroll
            for (int q = 0; q < 4; ++q) {
                float s[4][4];
                #pragma unroll
                for (int r = 0; r < 4; ++r)
                    #pragma unroll
                    for (int e = 0; e < 4; ++e) s[r][e] = 0.f;
                #pragma unroll
                for (int f = 0; f < 8; ++f) {
                    const ushort4 vv = *reinterpret_cast<const ushort4*>(vp + f * 16 + q * 4);
                    const float v0 = bf2f(vv.x), v1 = bf2f(vv.y), v2 = bf2f(vv.z), v3 = bf2f(vv.w);
                    #pragma unroll
                    for (int r = 0; r < 4; ++r) {
                        const float xf = xw[r][c+f];
                        s[r][0] = fmaf(xf, v0, s[r][0]);
                        s[r][1] = fmaf(xf, v1, s[r][1]);
                        s[r][2] = fmaf(xf, v2, s[r][2]);
                        s[r][3] = fmaf(xf, v3, s[r][3]);
                    }
                }
                #pragma unroll
                for (int r = 0; r < 4; ++r)
                    fmv[r] += s[r][0]*s[r][0] + s[r][1]*s[r][1] + s[r][2]*s[r][2] + s[r][3]*s[r][3];
            }
            #pragma unroll
            for (int r = 0; r < 4; ++r) outv[r] = lin[r] + 0.5f * (fmv[r] - sos[r]);
        }
        #pragma unroll
        for (int r = 0; r < 4; ++r)
            resb[(size_t)(r0 + r) * 2048 + 1024 + ch] = f2bf(outv[r]);
    }
}

// Final: out[b] = sigmoid(sum_{i<32} part[i][b] + b2)
__global__ __launch_bounds__(256) void final2_kernel(
    const float* __restrict__ part, const float* __restrict__ b2,
    float* __restrict__ out)
{
    const int b = blockIdx.x * 256 + threadIdx.x;
    float s = b2[0];
    #pragma unroll
    for (int i = 0; i < 32; ++i) s += part[(size_t)i * 2048 + b];
    out[b] = 1.f / (1.f + expf(-s));
}

extern "C" void kernel_launch(void* const* d_in, const int* in_sizes, int n_in,
                              void* d_out, int out_size, void* d_ws, size_t ws_size,
                              hipStream_t stream)
{
    const float* dx = (const float*)d_in[0];
    const float* cx = (const float*)d_in[1];
    const float* Wd = (const float*)d_in[2];
    const float* bd = (const float*)d_in[3];
    const float* Wc = (const float*)d_in[4];
    const float* bc = (const float*)d_in[5];
    const float* v  = (const float*)d_in[6];
    const float* lw = (const float*)d_in[7];
    const float* lb = (const float*)d_in[8];
    const float* W1 = (const float*)d_in[9];
    const float* b1 = (const float*)d_in[10];
    const float* W2 = (const float*)d_in[11];
    const float* b2 = (const float*)d_in[12];
    float* out = (float*)d_out;

    char* ws = (char*)d_ws;
    unsigned short* resb = (unsigned short*)(ws);                              // 8 MB
    float*          part = (float*)(ws + (8u << 20));                          // 256 KB
    unsigned short* dxb  = (unsigned short*)(ws + (9u << 20));                 // 2 MB
    unsigned short* cxb  = (unsigned short*)(ws + (11u << 20));                // 1 MB
    unsigned short* WdT  = (unsigned short*)(ws + (12u << 20));                // 512 KB
    unsigned short* WcT  = (unsigned short*)(ws + (12u << 20) + (512u << 10)); // 256 KB
    unsigned short* W1T  = (unsigned short*)(ws + (13u << 20));                // 4 MB
    unsigned short* vb   = (unsigned short*)(ws + (17u << 20));                // 255 KB
    float*          Ve   = (float*)(ws + (17u << 20) + (320u << 10));          // 32 KB
    float*          b1p  = (float*)(ws + (17u << 20) + (384u << 10));          // 4 KB
    float*          W2p  = (float*)(ws + (17u << 20) + (388u << 10));          // 4 KB

    const int prep_total = N_DX + N_CX + N_V + 1024 + 1024 + 8136;
    hipLaunchKernelGGL(prep_misc, dim3((prep_total + 255) / 256), dim3(256), 0, stream,
                       dx, cx, v, b1, W2, dxb, cxb, vb, b1p, W2p, Ve);
    hipLaunchKernelGGL(transpose_all, dim3(608), dim3(256), 0, stream,
                       Wd, Wc, W1, WdT, WcT, W1T);
    hipLaunchKernelGGL(gemm_top_mfma, dim3(256), dim3(512), 0, stream,
                       dxb, cxb, WdT, WcT, bd, bc, resb);
    hipLaunchKernelGGL(fm_kernel, dim3(512), dim3(256), 0, stream,
                       vb, Ve, lw, lb, resb);
    hipLaunchKernelGGL(gemm_w1_mfma, dim3(256), dim3(512), 0, stream,
                       resb, W1T, b1p, W2p, part);
    hipLaunchKernelGGL(final2_kernel, dim3(8), dim3(256), 0, stream,
                       part, b2, out);
}

// Round 5
// 66.305 us; speedup vs baseline: 5.3034x; 1.0267x over previous
//
#include <hip/hip_runtime.h>
#include <math.h>

// NDF=512 NCF=256 NCC=256 EMB=16 FIELD=8 B=2048
// NH0=1024 CHANNEL=1017 HID=1020 K3=2041
// resb: [2048][2048] bf16 (cols 0..1023 = x, 1024..2040 = x_fm2, 2041..2047 = 0)

typedef __bf16 bf16x8 __attribute__((ext_vector_type(8)));
typedef float  f32x4  __attribute__((ext_vector_type(4)));

__device__ __forceinline__ unsigned short f2bf(float x) {
    union { float f; unsigned u; } c; c.f = x;
    unsigned r = c.u + 0x7fffu + ((c.u >> 16) & 1u);
    return (unsigned short)(r >> 16);
}
__device__ __forceinline__ float bf2f(unsigned short u) {
    union { unsigned u; float f; } c; c.u = ((unsigned)u) << 16;
    return c.f;
}

#define GLDS(g, l) __builtin_amdgcn_global_load_lds( \
    (const __attribute__((address_space(1))) void*)(g), \
    (__attribute__((address_space(3))) void*)(l), 16, 0, 0)

// ---------------------------------------------------------------------------
// MFMA GEMM: C = act(A(bf16,MxK) @ B^T(bf16,[N][K]) + bias)
// BM=128 BN=64, K-step 128, 512 threads (8 waves).
// Quads split K within the tile: quad q = w>>2 handles k-cols [64q,64q+64).
// Wave tile 64x32 (sub = w&3: rows (sub>>1)*64, cols (sub&1)*32) -> 12 ds_read
// per 16 MFMA (21.3 flop/LDS-byte vs 16 before).
// 2-buffer LDS (96 KB), ONE barrier + vmcnt(0) per 128-K step: stage of t+1
// is issued after the barrier, targeting the buffer last read at step t-1
// (all reads drained before that barrier) -> race-free.
// Rows are 256B; XOR swizzle elem ^= (row&7)<<3 on BOTH sides (pre-swizzled
// global source for global_load_lds, same XOR on ds_read) -> each 8-lane
// group covers all 32 banks exactly once (conflict-free b128).
// Cross-quad acc reduction via LDS (aliased As) at the end.
// ---------------------------------------------------------------------------
template<int FUSE>   // FUSE 0: relu + bf16 store; FUSE 1: leaky + dot-W2 partials
__device__ __forceinline__ void mfma_gemm_body(
    const unsigned short* __restrict__ A, int lda,
    const unsigned short* __restrict__ B, int ldb,
    const float* __restrict__ bias,
    unsigned short* __restrict__ Cb, int ldc,                 // FUSE=0
    const float* __restrict__ W2p, float* __restrict__ part,  // FUSE=1
    int ccol0, int brow, int nbase, int K, int pcolb)
{
    __shared__ __align__(128) unsigned short As[2][128 * 128];  // 32KB x2
    __shared__ __align__(128) unsigned short Bs[2][64 * 128];   // 16KB x2

    const int t = threadIdx.x;
    const int w = t >> 6;
    const int l = t & 63;
    const int lr = l & 15, hi = l >> 4;
    const int lrx = (lr & 7) << 3;      // read-side swizzle XOR (elems)
    const int q   = w >> 2;             // k-half within the 128-K tile
    const int sub = w & 3;
    const int wr = sub >> 1, wc = sub & 1;
    const int kq = q << 6;              // quad k-elem base (0 or 64)

    f32x4 acc[4][2];
    #pragma unroll
    for (int m = 0; m < 4; ++m)
        #pragma unroll
        for (int n = 0; n < 2; ++n) acc[m][n] = f32x4{0.f, 0.f, 0.f, 0.f};

    const int nk = K >> 7;              // 128-K steps

    auto STAGE = [&](int buf, int k0) {
        #pragma unroll
        for (int i = 0; i < 4; ++i) {   // A: wave stages 16 rows (4 x 4-row instrs)
            const int r0 = w * 16 + i * 4;
            const int row = r0 + (l >> 4);
            const int se = ((l & 15) ^ (row & 7)) << 3;
            GLDS(A + (size_t)(brow + row) * lda + k0 + se, &As[buf][r0 * 128]);
        }
        #pragma unroll
        for (int i = 0; i < 2; ++i) {   // B: wave stages 8 rows
            const int r0 = w * 8 + i * 4;
            const int row = r0 + (l >> 4);
            const int se = ((l & 15) ^ (row & 7)) << 3;
            GLDS(B + (size_t)(nbase + row) * ldb + k0 + se, &Bs[buf][r0 * 128]);
        }
    };

    STAGE(0, 0);

    for (int tt = 0; tt < nk; ++tt) {
        asm volatile("s_waitcnt vmcnt(0)" ::: "memory");
        __builtin_amdgcn_s_barrier();
        if (tt + 1 < nk) STAGE((tt + 1) & 1, (tt + 1) << 7);

        const unsigned short* pa = &As[tt & 1][0];
        const unsigned short* pb = &Bs[tt & 1][0];
        bf16x8 af[4][2], bfv[2][2];
        #pragma unroll
        for (int m = 0; m < 4; ++m) {
            const int row = wr * 64 + m * 16 + lr;
            #pragma unroll
            for (int ks = 0; ks < 2; ++ks)
                af[m][ks] = *(const bf16x8*)&pa[row * 128 + ((kq + ks * 32 + hi * 8) ^ lrx)];
        }
        #pragma unroll
        for (int n = 0; n < 2; ++n) {
            const int row = wc * 32 + n * 16 + lr;
            #pragma unroll
            for (int ks = 0; ks < 2; ++ks)
                bfv[n][ks] = *(const bf16x8*)&pb[row * 128 + ((kq + ks * 32 + hi * 8) ^ lrx)];
        }
        #pragma unroll
        for (int ks = 0; ks < 2; ++ks)
            #pragma unroll
            for (int m = 0; m < 4; ++m)
                #pragma unroll
                for (int n = 0; n < 2; ++n)
                    acc[m][n] = __builtin_amdgcn_mfma_f32_16x16x32_bf16(af[m][ks], bfv[n][ks], acc[m][n], 0, 0, 0);
    }

    // Cross-quad reduction: quad1 writes accs to LDS (aliasing As), quad0 adds.
    __syncthreads();
    float* red = (float*)&As[0][0];     // 32 KB needed, 64 KB available
    if (q == 1) {
        #pragma unroll
        for (int m = 0; m < 4; ++m)
            #pragma unroll
            for (int n = 0; n < 2; ++n)
                *(f32x4*)&red[(((sub * 8) + m * 2 + n) * 64 + l) * 4] = acc[m][n];
    }
    __syncthreads();
    if (q != 0) return;

    #pragma unroll
    for (int m = 0; m < 4; ++m)
        #pragma unroll
        for (int n = 0; n < 2; ++n)
            acc[m][n] += *(const f32x4*)&red[(((sub * 8) + m * 2 + n) * 64 + l) * 4];

    // Epilogue. C/D map: col = lane&15, row = (lane>>4)*4 + j.
    const int orow0 = brow + wr * 64 + hi * 4;
    if (FUSE) {
        float bz[2], w2v[2];
        #pragma unroll
        for (int n = 0; n < 2; ++n) {
            const int col = ccol0 + wc * 32 + n * 16 + lr;
            bz[n] = bias[col];
            w2v[n] = W2p[col];
        }
        #pragma unroll
        for (int m = 0; m < 4; ++m) {
            #pragma unroll
            for (int j = 0; j < 4; ++j) {
                float p = 0.f;
                #pragma unroll
                for (int n = 0; n < 2; ++n) {
                    float z = acc[m][n][j] + bz[n];
                    z = (z > 0.f) ? z : 0.01f * z;
                    p = fmaf(z, w2v[n], p);
                }
                p += __shfl_xor(p, 1, 64);
                p += __shfl_xor(p, 2, 64);
                p += __shfl_xor(p, 4, 64);
                p += __shfl_xor(p, 8, 64);
                if (lr == 0)
                    part[(size_t)(pcolb + wc) * 2048 + orow0 + m * 16 + j] = p;
            }
        }
    } else {
        #pragma unroll
        for (int m = 0; m < 4; ++m) {
            #pragma unroll
            for (int n = 0; n < 2; ++n) {
                const int col = ccol0 + wc * 32 + n * 16 + lr;
                const float bz = bias[col];
                #pragma unroll
                for (int j = 0; j < 4; ++j) {
                    float z = acc[m][n][j] + bz;
                    z = fmaxf(z, 0.f);
                    Cb[(size_t)(orow0 + m * 16 + j) * ldc + col] = f2bf(z);
                }
            }
        }
    }
}

__global__ __launch_bounds__(512) void gemm_top_mfma(
    const unsigned short* __restrict__ dxb, const unsigned short* __restrict__ cxb,
    const unsigned short* __restrict__ WdT, const unsigned short* __restrict__ WcT,
    const float* __restrict__ bd, const float* __restrict__ bc,
    unsigned short* __restrict__ resb)
{
    const int bid = blockIdx.x;                   // 256 blocks
    const int swz = (bid & 7) * 32 + (bid >> 3);  // bijective XCD swizzle
    const int cb = swz & 15;
    const int brow = (swz >> 4) * 128;
    const int ccol0 = cb * 64;
    if (cb < 8)
        mfma_gemm_body<0>(dxb, 512, WdT, 512, bd, resb, 2048,
                          nullptr, nullptr, ccol0, brow, ccol0, 512, 0);
    else
        mfma_gemm_body<0>(cxb, 256, WcT, 256, bc - 512, resb, 2048,
                          nullptr, nullptr, ccol0, brow, ccol0 - 512, 256, 0);
}

__global__ __launch_bounds__(512) void gemm_w1_mfma(
    const unsigned short* __restrict__ resb, const unsigned short* __restrict__ W1T,
    const float* __restrict__ b1p, const float* __restrict__ W2p,
    float* __restrict__ part)
{
    const int bid = blockIdx.x;
    const int swz = (bid & 7) * 32 + (bid >> 3);
    const int cb = swz & 15;
    const int brow = (swz >> 4) * 128;
    mfma_gemm_body<1>(resb, 2048, W1T, 2048, b1p, nullptr, 0,
                      W2p, part, cb * 64, brow, cb * 64, 2048, cb * 2);
}

// ---------------------------------------------------------------------------
// prep_all: blocks 0..607 = transposes (Wd, Wc, W1 -> bf16 n-major);
//           blocks 608..  = elementwise prep (bf16 casts, pads, Ve).
// ---------------------------------------------------------------------------
#define N_DX (2048*512)
#define N_CX (2048*256)
#define N_V  (1017*128)
#define PREP_TOTAL (N_DX + N_CX + N_V + 1024 + 1024 + 8136)

__global__ __launch_bounds__(256) void prep_all(
    const float* __restrict__ dx, const float* __restrict__ cx,
    const float* __restrict__ v,  const float* __restrict__ b1,
    const float* __restrict__ W2,
    const float* __restrict__ Wd, const float* __restrict__ Wc, const float* __restrict__ W1,
    unsigned short* __restrict__ dxb, unsigned short* __restrict__ cxb,
    unsigned short* __restrict__ vb, float* __restrict__ b1p,
    float* __restrict__ W2p, float* __restrict__ Ve,
    unsigned short* __restrict__ WdT, unsigned short* __restrict__ WcT,
    unsigned short* __restrict__ W1T)
{
    __shared__ float tile[64][65];
    if (blockIdx.x < 608) {
        int bid = blockIdx.x;
        const float* in; unsigned short* out;
        int K0, N0, ldin, Kout, kt, nt;
        if (bid < 64) {
            in = Wd; out = WdT; K0 = 512; N0 = 512; ldin = 512; Kout = 512;
            kt = bid & 7; nt = bid >> 3;
        } else if (bid < 96) {
            bid -= 64;
            in = Wc; out = WcT; K0 = 256; N0 = 512; ldin = 512; Kout = 256;
            kt = bid & 3; nt = bid >> 2;
        } else {
            bid -= 96;
            in = W1; out = W1T; K0 = 2041; N0 = 1020; ldin = 1020; Kout = 2048;
            kt = bid & 31; nt = bid >> 5;
        }
        const int k0 = kt * 64, n0 = nt * 64;
        const int tt = threadIdx.x;
        const int nl = tt & 63, kq = tt >> 6;
        #pragma unroll
        for (int i = 0; i < 16; ++i) {
            const int kl = kq + i * 4;
            const int gk = k0 + kl, gn = n0 + nl;
            tile[kl][nl] = (gk < K0 && gn < N0) ? in[(size_t)gk * ldin + gn] : 0.f;
        }
        __syncthreads();
        const int kl2 = tt & 63, nq = tt >> 6;
        #pragma unroll
        for (int i = 0; i < 16; ++i) {
            const int nl2 = nq + i * 4;
            out[(size_t)(n0 + nl2) * Kout + k0 + kl2] = f2bf(tile[kl2][nl2]);
        }
        return;
    }
    int j = (blockIdx.x - 608) * 256 + threadIdx.x;
    if (j < N_DX) { dxb[j] = f2bf(dx[j]); return; }
    j -= N_DX;
    if (j < N_CX) { cxb[j] = f2bf(cx[j]); return; }
    j -= N_CX;
    if (j < N_V)  { vb[j] = f2bf(v[j]); return; }
    j -= N_V;
    if (j < 1024) { b1p[j] = (j < 1020) ? b1[j] : 0.f; return; }
    j -= 1024;
    if (j < 1024) { W2p[j] = (j < 1020) ? W2[j] : 0.f; return; }
    j -= 1024;
    if (j >= 8136) return;
    float s = 0.f;
    const float* vp = v + (size_t)j * 16;
    #pragma unroll
    for (int e = 0; e < 16; ++e) { float vv = bf2f(f2bf(vp[e])); s = fmaf(vv, vv, s); }
    Ve[j] = s;
}

// ---------------------------------------------------------------------------
// FM: 8 batch rows/block (256 blocks), thread: 4 consecutive channels.
// ---------------------------------------------------------------------------
__global__ __launch_bounds__(256) void fm_kernel(
    const unsigned short* __restrict__ vb, const float* __restrict__ Ve,
    const float* __restrict__ lin_w, const float* __restrict__ lin_b,
    unsigned short* __restrict__ resb)
{
    __shared__ float xs[8][1032];
    const int r0 = blockIdx.x * 8;
    const int t  = threadIdx.x;

    #pragma unroll
    for (int r = 0; r < 8; ++r) {
        const ushort4 u = reinterpret_cast<const ushort4*>(resb + (size_t)(r0 + r) * 2048)[t];
        xs[r][t*4+0] = bf2f(u.x); xs[r][t*4+1] = bf2f(u.y);
        xs[r][t*4+2] = bf2f(u.z); xs[r][t*4+3] = bf2f(u.w);
    }
    if (t < 8) {
        #pragma unroll
        for (int r = 0; r < 8; ++r) xs[r][1024 + t] = 0.f;
    }
    __syncthreads();

    float lw[8];
    #pragma unroll
    for (int f = 0; f < 8; ++f) lw[f] = lin_w[f];
    const float lb = lin_b[0];

    const int ch0 = t * 4;
    float xw[8][12];
    #pragma unroll
    for (int r = 0; r < 8; ++r) {
        const float4 a = *reinterpret_cast<const float4*>(&xs[r][ch0]);
        const float4 b = *reinterpret_cast<const float4*>(&xs[r][ch0 + 4]);
        const float4 c = *reinterpret_cast<const float4*>(&xs[r][ch0 + 8]);
        xw[r][0]=a.x; xw[r][1]=a.y; xw[r][2]=a.z; xw[r][3]=a.w;
        xw[r][4]=b.x; xw[r][5]=b.y; xw[r][6]=b.z; xw[r][7]=b.w;
        xw[r][8]=c.x; xw[r][9]=c.y; xw[r][10]=c.z; xw[r][11]=c.w;
    }

    #pragma unroll
    for (int c = 0; c < 4; ++c) {
        const int ch = ch0 + c;
        float outv[8] = {0,0,0,0,0,0,0,0};
        if (ch < 1017) {
            float lin[8], sos[8], fmv[8];
            #pragma unroll
            for (int r = 0; r < 8; ++r) { sos[r] = 0.f; fmv[r] = 0.f; }
            #pragma unroll
            for (int r = 0; r < 8; ++r) {
                float s = lb;
                #pragma unroll
                for (int f = 0; f < 8; ++f) s = fmaf(xw[r][c+f], lw[f], s);
                lin[r] = s;
            }
            #pragma unroll
            for (int f = 0; f < 8; ++f) {
                const float ve = Ve[ch * 8 + f];
                #pragma unroll
                for (int r = 0; r < 8; ++r)
                    sos[r] = fmaf(xw[r][c+f] * xw[r][c+f], ve, sos[r]);
            }
            const unsigned short* vp = vb + (size_t)ch * 128;
            #pragma unroll
            for (int qq = 0; qq < 4; ++qq) {
                float s[8][4];
                #pragma unroll
                for (int r = 0; r < 8; ++r)
                    #pragma unroll
                    for (int e = 0; e < 4; ++e) s[r][e] = 0.f;
                #pragma unroll
                for (int f = 0; f < 8; ++f) {
                    const ushort4 vv = *reinterpret_cast<const ushort4*>(vp + f * 16 + qq * 4);
                    const float v0 = bf2f(vv.x), v1 = bf2f(vv.y), v2 = bf2f(vv.z), v3 = bf2f(vv.w);
                    #pragma unroll
                    for (int r = 0; r < 8; ++r) {
                        const float xf = xw[r][c+f];
                        s[r][0] = fmaf(xf, v0, s[r][0]);
                        s[r][1] = fmaf(xf, v1, s[r][1]);
                        s[r][2] = fmaf(xf, v2, s[r][2]);
                        s[r][3] = fmaf(xf, v3, s[r][3]);
                    }
                }
                #pragma unroll
                for (int r = 0; r < 8; ++r)
                    fmv[r] += s[r][0]*s[r][0] + s[r][1]*s[r][1] + s[r][2]*s[r][2] + s[r][3]*s[r][3];
            }
            #pragma unroll
            for (int r = 0; r < 8; ++r) outv[r] = lin[r] + 0.5f * (fmv[r] - sos[r]);
        }
        #pragma unroll
        for (int r = 0; r < 8; ++r)
            resb[(size_t)(r0 + r) * 2048 + 1024 + ch] = f2bf(outv[r]);
    }
}

// Final: out[b] = sigmoid(sum_{i<32} part[i][b] + b2)
__global__ __launch_bounds__(256) void final2_kernel(
    const float* __restrict__ part, const float* __restrict__ b2,
    float* __restrict__ out)
{
    const int b = blockIdx.x * 256 + threadIdx.x;
    float s = b2[0];
    #pragma unroll
    for (int i = 0; i < 32; ++i) s += part[(size_t)i * 2048 + b];
    out[b] = 1.f / (1.f + expf(-s));
}

extern "C" void kernel_launch(void* const* d_in, const int* in_sizes, int n_in,
                              void* d_out, int out_size, void* d_ws, size_t ws_size,
                              hipStream_t stream)
{
    const float* dx = (const float*)d_in[0];
    const float* cx = (const float*)d_in[1];
    const float* Wd = (const float*)d_in[2];
    const float* bd = (const float*)d_in[3];
    const float* Wc = (const float*)d_in[4];
    const float* bc = (const float*)d_in[5];
    const float* v  = (const float*)d_in[6];
    const float* lw = (const float*)d_in[7];
    const float* lb = (const float*)d_in[8];
    const float* W1 = (const float*)d_in[9];
    const float* b1 = (const float*)d_in[10];
    const float* W2 = (const float*)d_in[11];
    const float* b2 = (const float*)d_in[12];
    float* out = (float*)d_out;

    char* ws = (char*)d_ws;
    unsigned short* resb = (unsigned short*)(ws);                              // 8 MB
    float*          part = (float*)(ws + (8u << 20));                          // 256 KB
    unsigned short* dxb  = (unsigned short*)(ws + (9u << 20));                 // 2 MB
    unsigned short* cxb  = (unsigned short*)(ws + (11u << 20));                // 1 MB
    unsigned short* WdT  = (unsigned short*)(ws + (12u << 20));                // 512 KB
    unsigned short* WcT  = (unsigned short*)(ws + (12u << 20) + (512u << 10)); // 256 KB
    unsigned short* W1T  = (unsigned short*)(ws + (13u << 20));                // 4 MB
    unsigned short* vb   = (unsigned short*)(ws + (17u << 20));                // 255 KB
    float*          Ve   = (float*)(ws + (17u << 20) + (320u << 10));          // 32 KB
    float*          b1p  = (float*)(ws + (17u << 20) + (384u << 10));          // 4 KB
    float*          W2p  = (float*)(ws + (17u << 20) + (388u << 10));          // 4 KB

    const int prep_blocks = 608 + (PREP_TOTAL + 255) / 256;
    hipLaunchKernelGGL(prep_all, dim3(prep_blocks), dim3(256), 0, stream,
                       dx, cx, v, b1, W2, Wd, Wc, W1,
                       dxb, cxb, vb, b1p, W2p, Ve, WdT, WcT, W1T);
    hipLaunchKernelGGL(gemm_top_mfma, dim3(256), dim3(512), 0, stream,
                       dxb, cxb, WdT, WcT, bd, bc, resb);
    hipLaunchKernelGGL(fm_kernel, dim3(256), dim3(256), 0, stream,
                       vb, Ve, lw, lb, resb);
    hipLaunchKernelGGL(gemm_w1_mfma, dim3(256), dim3(512), 0, stream,
                       resb, W1T, b1p, W2p, part);
    hipLaunchKernelGGL(final2_kernel, dim3(8), dim3(256), 0, stream,
                       part, b2, out);
}